// Round 1
// baseline (248.554 us; speedup 1.0000x reference)
//
#include <hip/hip_runtime.h>

#define D 256
#define BM 64
#define BN 128
#define BK 32

// Row sum-of-squares replicating numpy's pairwise summation order for n=256:
// split 128+128; each 128-block uses 8 strided accumulators r[j] = sum x[j+8i],
// combined as ((r0+r1)+(r2+r3))+((r4+r5)+(r6+r7)); then blk0+blk1.
// 16 lanes per row: lane = b*8 + j.
__global__ __launch_bounds__(256) void rowsq_np(const float* __restrict__ in,
                                                float* __restrict__ out, int nrows) {
    int t = blockIdx.x * 256 + threadIdx.x;
    int row = t >> 4;
    if (row >= nrows) return;
    int lane = t & 15;
    int b = lane >> 3, j = lane & 7;
    const float* p = in + (size_t)row * D + b * 128 + j;
    float r = 0.0f;
    {
#pragma clang fp contract(off)
        for (int i = 0; i < 16; ++i) {
            float v = p[8 * i];
            float sq = v * v;   // numpy squares elementwise first (separate rounding)
            r = r + sq;
        }
    }
    // fixed combine tree (matches numpy's pairwise combine; fp add is commutative)
    r += __shfl_xor(r, 1);
    r += __shfl_xor(r, 2);
    r += __shfl_xor(r, 4);
    r += __shfl_xor(r, 8);
    if (lane == 0) out[row] = r;
}

// Fused: dist GEMM tile + running argmin + final reduce + gather.
// Block: 64 rows x (all K codes in chunks of 128). 256 threads = (tx 16 codes-dim) x (ty 16 rows-dim).
// Micro-tile per thread: 4 rows x 8 codes (codes tx*4+j and 64+tx*4+j for contiguous LDS reads).
__global__ __launch_bounds__(256) void vq_main(
    const float* __restrict__ x, const float* __restrict__ cb,
    const float* __restrict__ x2, const float* __restrict__ e2,
    float* __restrict__ outq, float* __restrict__ outi, int K) {

    __shared__ float smem[BK * BM + BK * BN];   // Xs[BK][BM] ++ Es[BK][BN], 24 KB
    float* Xs = smem;
    float* Es = smem + BK * BM;

    const int tid = threadIdx.x;
    const int tx = tid & 15;
    const int ty = tid >> 4;
    const int n0 = blockIdx.x * BM;

    float bestD[4];
    int   bestI[4];
#pragma unroll
    for (int i = 0; i < 4; ++i) { bestD[i] = 3.4e38f; bestI[i] = 0; }

    float x2r[4];
#pragma unroll
    for (int i = 0; i < 4; ++i) x2r[i] = x2[n0 + ty * 4 + i];

    for (int kc = 0; kc < K; kc += BN) {
        float acc[4][8];
#pragma unroll
        for (int i = 0; i < 4; ++i)
#pragma unroll
            for (int j = 0; j < 8; ++j) acc[i][j] = 0.0f;

        for (int d0 = 0; d0 < D; d0 += BK) {
            __syncthreads();
            // stage X tile (64 rows x 32 d), transposed -> Xs[d][m]
            {
                int dof = (tid & 7) * 4;
                int m = tid >> 3;
#pragma unroll
                for (int r = 0; r < 2; ++r) {
                    int mm = m + r * 32;
                    const float4 v = *(const float4*)(x + (size_t)(n0 + mm) * D + d0 + dof);
                    Xs[(dof + 0) * BM + mm] = v.x;
                    Xs[(dof + 1) * BM + mm] = v.y;
                    Xs[(dof + 2) * BM + mm] = v.z;
                    Xs[(dof + 3) * BM + mm] = v.w;
                }
            }
            // stage E tile (128 codes x 32 d), transposed -> Es[d][k]
            {
                int k = tid >> 1;
                int dbase = (tid & 1) * 16;
#pragma unroll
                for (int r = 0; r < 4; ++r) {
                    int dd = dbase + r * 4;
                    const float4 v = *(const float4*)(cb + (size_t)(kc + k) * D + d0 + dd);
                    Es[(dd + 0) * BN + k] = v.x;
                    Es[(dd + 1) * BN + k] = v.y;
                    Es[(dd + 2) * BN + k] = v.z;
                    Es[(dd + 3) * BN + k] = v.w;
                }
            }
            __syncthreads();
#pragma unroll
            for (int d = 0; d < BK; ++d) {
                float4 xv = *(const float4*)(Xs + d * BM + ty * 4);
                float4 e0 = *(const float4*)(Es + d * BN + tx * 4);
                float4 e1 = *(const float4*)(Es + d * BN + 64 + tx * 4);
                float xa[4] = {xv.x, xv.y, xv.z, xv.w};
                float ea[8] = {e0.x, e0.y, e0.z, e0.w, e1.x, e1.y, e1.z, e1.w};
#pragma unroll
                for (int i = 0; i < 4; ++i)
#pragma unroll
                    for (int j = 0; j < 8; ++j)
                        acc[i][j] = fmaf(xa[i], ea[j], acc[i][j]);
            }
        }
        // distances + running argmin (scan in ascending code index for first-min tie-break)
#pragma unroll
        for (int j = 0; j < 8; ++j) {
            int kk = kc + ((j < 4) ? (tx * 4 + j) : (64 + tx * 4 + (j - 4)));
            float e2v = e2[kk];
#pragma unroll
            for (int i = 0; i < 4; ++i) {
                float s = x2r[i] + e2v;            // matches ref: (x2 + e2) first
                float dist = s - 2.0f * acc[i][j]; // single rounding == ref's sub
                if (dist < bestD[i]) { bestD[i] = dist; bestI[i] = kk; }
            }
        }
    }

    // cross-tx reduction via LDS (alias tile memory; all tile reads are done)
    __syncthreads();
    float* redD   = smem;                       // [BM][16]
    int*   redI   = (int*)(smem + BM * 16);     // [BM][16]
    int*   idxRow = (int*)(smem + 2 * BM * 16); // [BM]
#pragma unroll
    for (int i = 0; i < 4; ++i) {
        redD[(ty * 4 + i) * 16 + tx] = bestD[i];
        redI[(ty * 4 + i) * 16 + tx] = bestI[i];
    }
    __syncthreads();
    if (tid < BM) {
        float bd = 3.4e38f;
        int bi = 0x7fffffff;
        for (int t = 0; t < 16; ++t) {
            float dv = redD[tid * 16 + t];
            int   ix = redI[tid * 16 + t];
            if (dv < bd || (dv == bd && ix < bi)) { bd = dv; bi = ix; }
        }
        idxRow[tid] = bi;
        outi[n0 + tid] = (float)bi;
    }
    __syncthreads();
    // gather: one wave per row, float4 per lane
#pragma unroll
    for (int rep = 0; rep < 16; ++rep) {
        int r = rep * 4 + (tid >> 6);
        int lane = tid & 63;
        int code = idxRow[r];
        float4 v = *(const float4*)(cb + (size_t)code * D + lane * 4);
        *(float4*)(outq + (size_t)(n0 + r) * D + lane * 4) = v;
    }
}

extern "C" void kernel_launch(void* const* d_in, const int* in_sizes, int n_in,
                              void* d_out, int out_size, void* d_ws, size_t ws_size,
                              hipStream_t stream) {
    const float* x  = (const float*)d_in[0];
    const float* cb = (const float*)d_in[1];
    const int N = in_sizes[0] / D;   // 32768
    const int K = in_sizes[1] / D;   // 1024

    float* outq = (float*)d_out;
    float* outi = outq + (size_t)N * D;   // indices-as-float region

    // x2 staged in the indices output region (each block consumes its own rows'
    // x2 before overwriting with the final index -> no cross-block hazard).
    float* x2 = outi;
    float* e2 = (float*)d_ws;             // K floats = 4 KB

    rowsq_np<<<(N * 16 + 255) / 256, 256, 0, stream>>>(x, x2, N);
    rowsq_np<<<(K * 16 + 255) / 256, 256, 0, stream>>>(cb, e2, K);
    vq_main<<<N / BM, 256, 0, stream>>>(x, cb, x2, e2, outq, outi, K);
}

// Round 3
// 119.267 us; speedup vs baseline: 2.0840x; 2.0840x over previous
//
#include <hip/hip_runtime.h>
#include <hip/hip_bf16.h>

#define D 256

typedef __attribute__((ext_vector_type(8))) short  s16x8;   // 8 bf16 bit-patterns
typedef __attribute__((ext_vector_type(4))) float  f4_t;
typedef unsigned long long ull;

// ---------------- rowsq replicating numpy pairwise order --------------------
__global__ __launch_bounds__(256) void rowsq_np(const float* __restrict__ in,
                                                float* __restrict__ out, int nrows) {
    int t = blockIdx.x * 256 + threadIdx.x;
    int row = t >> 4;
    if (row >= nrows) return;
    int lane = t & 15;
    int b = lane >> 3, j = lane & 7;
    const float* p = in + (size_t)row * D + b * 128 + j;
    float r = 0.0f;
    {
#pragma clang fp contract(off)
        for (int i = 0; i < 16; ++i) { float v = p[8 * i]; float sq = v * v; r = r + sq; }
    }
    r += __shfl_xor(r, 1);
    r += __shfl_xor(r, 2);
    r += __shfl_xor(r, 4);
    r += __shfl_xor(r, 8);
    if (lane == 0) out[row] = r;
}

// ------------- split fp32 -> (hi,lo) bf16 in MFMA-fragment panel order ------
// element (row,k) -> p*4096 + (s*64 + chunk*16 + rr)*8 + e ; p=row>>4, rr=row&15,
// s=k>>5, chunk=(k&31)>>3, e=k&7.  A wave fragment read = panel_base + lane*8.
__global__ __launch_bounds__(256) void split_perm(const float* __restrict__ in,
    short* __restrict__ hi, short* __restrict__ lo) {
    __shared__ float tile[16 * 264];
    const int t = threadIdx.x;
    const int p = blockIdx.x;
    const float* src = in + (size_t)p * 16 * 256;
#pragma unroll
    for (int it = 0; it < 4; ++it) {
        int idx = it * 256 + t;
        int row = idx >> 6, c4 = idx & 63;
        float4 v = *(const float4*)(src + row * 256 + c4 * 4);
        *(float4*)(tile + row * 264 + c4 * 4) = v;
    }
    __syncthreads();
#pragma unroll
    for (int j = 0; j < 2; ++j) {
        int sl = j * 256 + t;                      // slot 0..511
        int s = sl >> 6, chunk = (sl >> 4) & 3, rr = sl & 15;
        const float* q = tile + rr * 264 + s * 32 + chunk * 8;
        s16x8 h8, l8;
#pragma unroll
        for (int e = 0; e < 8; ++e) {
            float v = q[e];
            __hip_bfloat16 hb = __float2bfloat16(v);
            float hf = __bfloat162float(hb);
            __hip_bfloat16 lb = __float2bfloat16(v - hf);
            h8[e] = (short)__builtin_bit_cast(unsigned short, hb);
            l8[e] = (short)__builtin_bit_cast(unsigned short, lb);
        }
        size_t off = (size_t)p * 4096 + (size_t)sl * 8;
        *(s16x8*)(hi + off) = h8;
        *(s16x8*)(lo + off) = l8;
    }
}

// ---------------- main MFMA kernel: xe GEMM + top-2 candidates --------------
// Block: 32 rows x 512 codes (one half). 4 waves split the codes (128 each).
// A (x hi/lo) staged to LDS once; B (codebook hi/lo) streamed from L2 to regs.
// Selection keys are 64-bit: (fp32 bits of v) << 32 | code  -> exact ordering,
// ties broken toward the smaller code index. Top-2 kept per half.
__global__ __launch_bounds__(256, 2) void vq_gemm(
    const short* __restrict__ Xhi, const short* __restrict__ Xlo,
    const short* __restrict__ Ehi, const short* __restrict__ Elo,
    const float* __restrict__ e2, int* __restrict__ cand) {
    __shared__ short As[16384];                  // [buf2][m2][s8][512] bf16
    const int tid = threadIdx.x;
    const int l = tid & 63;
    const int w = tid >> 6;
    const int rb = blockIdx.x & 1023;            // N/32 = 1024 row-blocks
    const int h  = blockIdx.x >> 10;             // code half
    const int R0 = rb * 32;
    const int p0 = R0 >> 4;

    // stage A tile (32 rows x 256 k, hi+lo = 32 KB) once, linear writes
#pragma unroll
    for (int j = 0; j < 8; ++j) {
        int c = w + j * 4;
        int buf = c >> 4, m = (c >> 3) & 1, s = c & 7;
        const short* sp = (buf ? Xlo : Xhi) + (size_t)((p0 + m) * 8 + s) * 512 + l * 8;
        *(s16x8*)(As + c * 512 + l * 8) = *(const s16x8*)sp;
    }
    __syncthreads();

    const int C0 = h * 512 + w * 128;
    const int pc0 = C0 >> 4;

    f4_t acc[2][8];
#pragma unroll
    for (int m = 0; m < 2; ++m)
#pragma unroll
        for (int n = 0; n < 8; ++n) { f4_t z = {0.f,0.f,0.f,0.f}; acc[m][n] = z; }

#pragma unroll 1
    for (int s = 0; s < 8; ++s) {
        s16x8 ah[2], al[2];
#pragma unroll
        for (int m = 0; m < 2; ++m) {
            ah[m] = *(const s16x8*)(As + (m * 8 + s) * 512 + l * 8);
            al[m] = *(const s16x8*)(As + 8192 + (m * 8 + s) * 512 + l * 8);
        }
        s16x8 bh[8], bl[8];
#pragma unroll
        for (int n = 0; n < 8; ++n) {
            size_t boff = (size_t)((pc0 + n) * 8 + s) * 512 + l * 8;
            bh[n] = *(const s16x8*)(Ehi + boff);
            bl[n] = *(const s16x8*)(Elo + boff);
        }
#pragma unroll
        for (int n = 0; n < 8; ++n)
#pragma unroll
            for (int m = 0; m < 2; ++m) {
                acc[m][n] = __builtin_amdgcn_mfma_f32_16x16x32_bf16(ah[m], bh[n], acc[m][n], 0, 0, 0);
                acc[m][n] = __builtin_amdgcn_mfma_f32_16x16x32_bf16(ah[m], bl[n], acc[m][n], 0, 0, 0);
                acc[m][n] = __builtin_amdgcn_mfma_f32_16x16x32_bf16(al[m], bh[n], acc[m][n], 0, 0, 0);
            }
    }

    // epilogue: exact 64-bit-key running top-2 per row-slot
    // v = 0.5*e2 + 256 - xe  (>0, so fp32 bits order as uint); key = bits<<32 | code
    ull k1[2][4], k2[2][4];
#pragma unroll
    for (int m = 0; m < 2; ++m)
#pragma unroll
        for (int r = 0; r < 4; ++r) { k1[m][r] = ~0ull; k2[m][r] = ~0ull; }
#pragma unroll
    for (int n = 0; n < 8; ++n) {
        int code = C0 + n * 16 + (l & 15);
        float e2b = 0.5f * e2[code] + 256.0f;
#pragma unroll
        for (int m = 0; m < 2; ++m)
#pragma unroll
            for (int r = 0; r < 4; ++r) {
                float v = e2b - acc[m][n][r];
                ull key = ((ull)__builtin_bit_cast(unsigned int, v) << 32) | (unsigned int)code;
                ull mx = k1[m][r] > key ? k1[m][r] : key;
                k1[m][r] = k1[m][r] < key ? k1[m][r] : key;
                k2[m][r] = k2[m][r] < mx ? k2[m][r] : mx;
            }
    }
    // reduce top-2 across the 16 lanes sharing the same rows
#pragma unroll
    for (int m = 0; m < 2; ++m)
#pragma unroll
        for (int r = 0; r < 4; ++r) {
            ull a = k1[m][r], b = k2[m][r];
#pragma unroll
            for (int msk = 1; msk < 16; msk <<= 1) {
                ull oa = __shfl_xor(a, msk);
                ull ob = __shfl_xor(b, msk);
                ull hi_ = a > oa ? a : oa;
                a = a < oa ? a : oa;
                b = b < ob ? b : ob;
                b = b < hi_ ? b : hi_;
            }
            k1[m][r] = a; k2[m][r] = b;
        }
    // merge across the 4 waves (disjoint code ranges) via LDS
    __syncthreads();
    ull* mrg = (ull*)As;                         // [32 rows][4 waves][2]
    if ((l & 15) == 0) {
#pragma unroll
        for (int m = 0; m < 2; ++m)
#pragma unroll
            for (int r = 0; r < 4; ++r) {
                int rloc = m * 16 + (l >> 4) * 4 + r;
                mrg[(rloc * 4 + w) * 2 + 0] = k1[m][r];
                mrg[(rloc * 4 + w) * 2 + 1] = k2[m][r];
            }
    }
    __syncthreads();
    if (tid < 32) {
        ull a = ~0ull, b = ~0ull;
#pragma unroll
        for (int ww = 0; ww < 4; ++ww) {
            ull oa = mrg[(tid * 4 + ww) * 2 + 0];
            ull ob = mrg[(tid * 4 + ww) * 2 + 1];
            ull hi_ = a > oa ? a : oa;
            a = a < oa ? a : oa;
            b = b < ob ? b : ob;
            b = b < hi_ ? b : hi_;
        }
        int2 c2; c2.x = (int)(a & 1023ull); c2.y = (int)(b & 1023ull);
        *(int2*)(cand + (size_t)(R0 + tid) * 4 + h * 2) = c2;
    }
}

// ------- reference-replicating fp32 re-compare of the 4 candidates ----------
// dist = (x2_np + e2_np) - 2*xe  -- same formula, same quantization, same
// first-index tie-break as numpy's argmin (this is what round-1 validated).
__global__ __launch_bounds__(256) void vq_decide(const float* __restrict__ x,
    const float* __restrict__ cb, const int* __restrict__ cand,
    const float* __restrict__ x2, const float* __restrict__ e2,
    float* __restrict__ outi) {
    const int w = threadIdx.x >> 6, l = threadIdx.x & 63;
    const int row = blockIdx.x * 4 + w;
    int4 c = *(const int4*)(cand + (size_t)row * 4);
    int q = l >> 4, jj = l & 15;
    int ci = q == 0 ? c.x : q == 1 ? c.y : q == 2 ? c.z : c.w;
    const float* e = cb + (size_t)ci * D;
    const float* xr = x + (size_t)row * D;
    float xe = 0.f;
#pragma unroll
    for (int i = 0; i < 4; ++i) {
        float4 ev = *(const float4*)(e + jj * 16 + i * 4);
        float4 xv = *(const float4*)(xr + jj * 16 + i * 4);
        xe = fmaf(xv.x, ev.x, xe); xe = fmaf(xv.y, ev.y, xe);
        xe = fmaf(xv.z, ev.z, xe); xe = fmaf(xv.w, ev.w, xe);
    }
#pragma unroll
    for (int m = 1; m < 16; m <<= 1) xe += __shfl_xor(xe, m);
    float s = x2[row] + e2[ci];                  // ref order: (x2 + e2) first
    float dq = s - 2.f * xe;                     // then - 2*xe (same rounding as ref)
    float best = 3.4e38f; int bi = 0x7fffffff;
#pragma unroll
    for (int qq = 0; qq < 4; ++qq) {
        float dd = __shfl(dq, qq * 16);
        int   ii = __shfl(ci, qq * 16);
        if (dd < best || (dd == best && ii < bi)) { best = dd; bi = ii; }
    }
    if (l == 0) outi[row] = (float)bi;
}

// ---------------- gather winners into the quantized output ------------------
__global__ __launch_bounds__(256) void vq_gather(const float* __restrict__ cb,
    const float* __restrict__ outi, float* __restrict__ outq) {
    const int w = threadIdx.x >> 6, l = threadIdx.x & 63;
    const int row = blockIdx.x * 4 + w;
    int ci = (int)outi[row];
    float4 v = *(const float4*)(cb + (size_t)ci * D + l * 4);
    *(float4*)(outq + (size_t)row * D + l * 4) = v;
}

extern "C" void kernel_launch(void* const* d_in, const int* in_sizes, int n_in,
                              void* d_out, int out_size, void* d_ws, size_t ws_size,
                              hipStream_t stream) {
    const float* x  = (const float*)d_in[0];
    const float* cb = (const float*)d_in[1];
    const int N  = in_sizes[0] / D;   // 32768
    const int Kc = in_sizes[1] / D;   // 1024

    float* outq = (float*)d_out;
    float* outi = outq + (size_t)N * D;

    const size_t needX = (size_t)N * D * 2 * 2;   // hi+lo bf16, 32 MB
    const size_t needS = (size_t)Kc * D * 2 * 2 + (size_t)Kc * 4
                       + (size_t)N * 4 + (size_t)N * 16;

    short *Xhi, *Xlo; char* small;
    if (ws_size >= needX + needS) {
        Xhi = (short*)d_ws;
        Xlo = Xhi + (size_t)N * D;
        small = (char*)d_ws + needX;
    } else {
        // X splits live in d_out[0,32MB); outi (last 128KB) doesn't overlap.
        // vq_gather overwrites them only after vq_decide is done (stream order).
        Xhi = (short*)d_out;
        Xlo = Xhi + (size_t)N * D;
        small = (char*)d_ws;                      // needs ~1.8 MB
    }
    short* Ehi = (short*)small;
    short* Elo = Ehi + (size_t)Kc * D;
    float* e2  = (float*)(Elo + (size_t)Kc * D);
    float* x2  = e2 + Kc;
    int*  cand = (int*)(x2 + N);

    split_perm<<<N / 16, 256, 0, stream>>>(x, Xhi, Xlo);
    split_perm<<<Kc / 16, 256, 0, stream>>>(cb, Ehi, Elo);
    rowsq_np<<<(Kc * 16) / 256, 256, 0, stream>>>(cb, e2, Kc);
    rowsq_np<<<(N * 16) / 256, 256, 0, stream>>>(x, x2, N);
    vq_gemm<<<(N / 32) * 2, 256, 0, stream>>>(Xhi, Xlo, Ehi, Elo, e2, cand);
    vq_decide<<<N / 4, 256, 0, stream>>>(x, cb, cand, x2, e2, outi);
    vq_gather<<<N / 4, 256, 0, stream>>>(cb, outi, outq);
}